// Round 13
// baseline (37.655 us; speedup 1.0000x reference)
//
#include <hip/hip_runtime.h>

#define NCH 8
#define CACHE 12   // float4 per lane -> covers ~2 frustums (combined <= 768 points)

typedef float v4f __attribute__((ext_vector_type(4)));

__device__ __forceinline__ void acc4(const float4& v, float4& sum, float4& sq, float4& mx) {
    sum.x += v.x; sq.x += v.x * v.x; mx.x = fmaxf(mx.x, v.x);
    sum.y += v.y; sq.y += v.y * v.y; mx.y = fmaxf(mx.y, v.y);
    sum.z += v.z; sq.z += v.z * v.z; mx.z = fmaxf(mx.z, v.z);
    sum.w += v.w; sq.w += v.w * v.w; mx.w = fmaxf(mx.w, v.w);
}

// Wave-cooperative lower_bound: smallest idx with a[idx] >= key. 4 memory rounds for n=2M.
__device__ __forceinline__ int wave_lower_bound(const int* __restrict__ a, int n, int key,
                                                int lane) {
    int lo = 0, len = n;
    while (len > 64) {
        int step = (len + 63) >> 6;                       // ceil(len/64)
        int p = lo + lane * step;
        int v = (p < lo + len) ? a[p] : 0x7fffffff;
        unsigned long long bal = __ballot(v < key);
        int cnt = __popcll(bal);                          // preds form a prefix (sorted)
        if (cnt == 0) return lo;
        int nlo = lo + (cnt - 1) * step + 1;
        int nhi = lo + len;
        int cap = lo + cnt * step;
        if (cnt < 64 && cap < nhi) nhi = cap;
        lo = nlo; len = nhi - nlo;
    }
    int v = (lane < len) ? a[lo + lane] : 0x7fffffff;
    unsigned long long bal = __ballot(v < key);
    return lo + __popcll(bal);
}

// Reduce across lanes differing in bits 1..5: lane l ends with totals for parity l&1
// (parity p owns channels [4p, 4p+4)).
__device__ __forceinline__ void wreduce(float4& sum, float4& sq, float4& mx) {
    #pragma unroll
    for (int m = 2; m <= 32; m <<= 1) {
        sum.x += __shfl_xor(sum.x, m, 64);
        sum.y += __shfl_xor(sum.y, m, 64);
        sum.z += __shfl_xor(sum.z, m, 64);
        sum.w += __shfl_xor(sum.w, m, 64);
        sq.x  += __shfl_xor(sq.x,  m, 64);
        sq.y  += __shfl_xor(sq.y,  m, 64);
        sq.z  += __shfl_xor(sq.z,  m, 64);
        sq.w  += __shfl_xor(sq.w,  m, 64);
        mx.x = fmaxf(mx.x, __shfl_xor(mx.x, m, 64));
        mx.y = fmaxf(mx.y, __shfl_xor(mx.y, m, 64));
        mx.z = fmaxf(mx.z, __shfl_xor(mx.z, m, 64));
        mx.w = fmaxf(mx.w, __shfl_xor(mx.w, m, 64));
    }
}

__device__ __forceinline__ void mk_stats(const float4& sum, const float4& sq, float cnt,
                                         float4& mean, float4& sd, float4& dv) {
    const float invc = 1.0f / fmaxf(cnt, 1.0f);
    mean.x = sum.x * invc; mean.y = sum.y * invc; mean.z = sum.z * invc; mean.w = sum.w * invc;
    float vx = fmaxf(sq.x * invc - mean.x * mean.x, 0.0f);
    float vy = fmaxf(sq.y * invc - mean.y * mean.y, 0.0f);
    float vz = fmaxf(sq.z * invc - mean.z * mean.z, 0.0f);
    float vw = fmaxf(sq.w * invc - mean.w * mean.w, 0.0f);
    sd.x = sqrtf(vx); sd.y = sqrtf(vy); sd.z = sqrtf(vz); sd.w = sqrtf(vw);
    dv.x = 1.0f / (sd.x > 0.f ? sd.x : 1.f);
    dv.y = 1.0f / (sd.y > 0.f ? sd.y : 1.f);
    dv.z = 1.0f / (sd.z > 0.f ? sd.z : 1.f);
    dv.w = 1.0f / (sd.w > 0.f ? sd.w : 1.f);
}

// One WAVE per TWO adjacent frustums (i_frustum sorted, i_inv identity -> contiguous,
// adjacent slices). One 64-ary cooperative search per wave; segment split at E0.
// 7200 waves ~= one scheduling round of the 8192 wave slots.
__global__ __launch_bounds__(128) void k_fused2(
    const float* __restrict__ pc, const int* __restrict__ i_frustum,
    const float* __restrict__ counts, int n, int F,
    float* __restrict__ out_mean, float* __restrict__ out_std,
    float* __restrict__ out_max, float* __restrict__ out_pcn)
{
    const int wid = (blockIdx.x * blockDim.x + threadIdx.x) >> 6;  // global wave id
    const int f0 = wid * 2;
    if (f0 >= F) return;                                           // wave-uniform exit
    const int f1 = f0 + 1;
    const int lane = threadIdx.x & 63;

    const int s0 = wave_lower_bound(i_frustum, n, f0, lane);
    const float c0 = counts[f0];
    const float c1 = (f1 < F) ? counts[f1] : 0.0f;   // counts are small ints, exact in float
    const int e0 = s0 + (int)c0;
    const int e1 = e0 + (int)c1;

    const float4* __restrict__ pc4 = reinterpret_cast<const float4*>(pc);
    v4f* __restrict__ out4 = reinterpret_cast<v4f*>(out_pcn);

    const int B = s0 * 2, E0 = e0 * 2, E1 = e1 * 2;  // float4-granular (2 float4/point)

    float4 sum0 = {0,0,0,0}, sq0 = {0,0,0,0}, mx0 = {0,0,0,0};  // 0-init == include_self max
    float4 sum1 = {0,0,0,0}, sq1 = {0,0,0,0}, mx1 = {0,0,0,0};
    float4 c[CACHE];

    // Issue all loads up-front (predicated) for MLP, then accumulate per segment.
    int k = B + lane;
    #pragma unroll
    for (int u = 0; u < CACHE; ++u) {
        if (k < E1) c[u] = pc4[k];
        k += 64;
    }
    k = B + lane;
    #pragma unroll
    for (int u = 0; u < CACHE; ++u) {
        if (k < E1) {
            if (k < E0) acc4(c[u], sum0, sq0, mx0);
            else        acc4(c[u], sum1, sq1, mx1);
        }
        k += 64;
    }
    for (int kk = k; kk < E1; kk += 64) {  // rare overflow beyond CACHE
        float4 v = pc4[kk];
        if (kk < E0) acc4(v, sum0, sq0, mx0);
        else         acc4(v, sum1, sq1, mx1);
    }

    wreduce(sum0, sq0, mx0);
    wreduce(sum1, sq1, mx1);

    float4 mean0, sd0, dv0, mean1, sd1, dv1;
    mk_stats(sum0, sq0, c0, mean0, sd0, dv0);
    mk_stats(sum1, sq1, c1, mean1, sd1, dv1);

    // lanes 0,1 write f0 stats; lanes 2,3 write f1 stats (lane parity picks channel half).
    if (lane < 2) {
        reinterpret_cast<float4*>(out_mean + (size_t)f0 * NCH)[lane] = mean0;
        reinterpret_cast<float4*>(out_std  + (size_t)f0 * NCH)[lane] = sd0;
        reinterpret_cast<float4*>(out_max  + (size_t)f0 * NCH)[lane] = mx0;
    } else if (lane < 4 && f1 < F) {
        reinterpret_cast<float4*>(out_mean + (size_t)f1 * NCH)[lane & 1] = mean1;
        reinterpret_cast<float4*>(out_std  + (size_t)f1 * NCH)[lane & 1] = sd1;
        reinterpret_cast<float4*>(out_max  + (size_t)f1 * NCH)[lane & 1] = mx1;
    }

    // Normalize (per-element segment select) + non-temporal stores.
    k = B + lane;
    #pragma unroll
    for (int u = 0; u < CACHE; ++u) {
        if (k < E1) {
            const bool s0b = k < E0;
            v4f o;
            o.x = (c[u].x - (s0b ? mean0.x : mean1.x)) * (s0b ? dv0.x : dv1.x);
            o.y = (c[u].y - (s0b ? mean0.y : mean1.y)) * (s0b ? dv0.y : dv1.y);
            o.z = (c[u].z - (s0b ? mean0.z : mean1.z)) * (s0b ? dv0.z : dv1.z);
            o.w = (c[u].w - (s0b ? mean0.w : mean1.w)) * (s0b ? dv0.w : dv1.w);
            __builtin_nontemporal_store(o, &out4[k]);
        }
        k += 64;
    }
    for (int kk = k; kk < E1; kk += 64) {  // rare overflow
        float4 v = pc4[kk];
        const bool s0b = kk < E0;
        v4f o;
        o.x = (v.x - (s0b ? mean0.x : mean1.x)) * (s0b ? dv0.x : dv1.x);
        o.y = (v.y - (s0b ? mean0.y : mean1.y)) * (s0b ? dv0.y : dv1.y);
        o.z = (v.z - (s0b ? mean0.z : mean1.z)) * (s0b ? dv0.z : dv1.z);
        o.w = (v.w - (s0b ? mean0.w : mean1.w)) * (s0b ? dv0.w : dv1.w);
        __builtin_nontemporal_store(o, &out4[kk]);
    }
}

extern "C" void kernel_launch(void* const* d_in, const int* in_sizes, int n_in,
                              void* d_out, int out_size, void* d_ws, size_t ws_size,
                              hipStream_t stream) {
    const float* pc        = (const float*)d_in[0];
    const int*   i_frustum = (const int*)d_in[1];
    const float* counts    = (const float*)d_in[3];

    int n = in_sizes[0] / NCH;   // 2,000,000 points
    int F = in_sizes[3];         // 14,400 frustums

    float* out_mean = (float*)d_out;
    float* out_std  = out_mean + (size_t)F * NCH;
    float* out_max  = out_std  + (size_t)F * NCH;
    float* out_pcn  = out_max  + (size_t)F * NCH;

    int nwaves = (F + 1) / 2;                    // one wave per 2 frustums
    int waves_per_block = 128 / 64;
    int blocks = (nwaves + waves_per_block - 1) / waves_per_block;
    k_fused2<<<blocks, 128, 0, stream>>>(pc, i_frustum, counts, n, F,
                                         out_mean, out_std, out_max, out_pcn);
}

// Round 14
// 32.877 us; speedup vs baseline: 1.1453x; 1.1453x over previous
//
#include <hip/hip_runtime.h>

#define NCH 8
#define CACHE 8   // float4 per lane -> covers segments up to 256 points per frustum

typedef float v4f __attribute__((ext_vector_type(4)));

__device__ __forceinline__ void acc4(const float4& v, float4& sum, float4& sq, float4& mx) {
    sum.x += v.x; sq.x += v.x * v.x; mx.x = fmaxf(mx.x, v.x);
    sum.y += v.y; sq.y += v.y * v.y; mx.y = fmaxf(mx.y, v.y);
    sum.z += v.z; sq.z += v.z * v.z; mx.z = fmaxf(mx.z, v.z);
    sum.w += v.w; sq.w += v.w * v.w; mx.w = fmaxf(mx.w, v.w);
}

__device__ __forceinline__ v4f norm4(const float4& v, const float4& m, const float4& d) {
    v4f o;
    o.x = (v.x - m.x) * d.x;
    o.y = (v.y - m.y) * d.y;
    o.z = (v.z - m.z) * d.z;
    o.w = (v.w - m.w) * d.w;
    return o;
}

// Wave-cooperative lower_bound: smallest idx with a[idx] >= key. 4 memory rounds for n=2M.
__device__ __forceinline__ int wave_lower_bound(const int* __restrict__ a, int n, int key,
                                                int lane) {
    int lo = 0, len = n;
    while (len > 64) {
        int step = (len + 63) >> 6;                       // ceil(len/64)
        int p = lo + lane * step;
        int v = (p < lo + len) ? a[p] : 0x7fffffff;
        unsigned long long bal = __ballot(v < key);
        int cnt = __popcll(bal);                          // preds form a prefix (sorted)
        if (cnt == 0) return lo;
        int nlo = lo + (cnt - 1) * step + 1;
        int nhi = lo + len;
        int cap = lo + cnt * step;
        if (cnt < 64 && cap < nhi) nhi = cap;
        lo = nlo; len = nhi - nlo;
    }
    int v = (lane < len) ? a[lo + lane] : 0x7fffffff;
    unsigned long long bal = __ballot(v < key);
    return lo + __popcll(bal);
}

// Single fused dispatch: one WAVE per frustum (i_frustum sorted, i_inv identity ->
// contiguous slices). Wave-cooperative 64-ary search finds the segment start; end =
// start + counts[f]. One streaming pass: load, shuffle reduce (no LDS/barriers),
// redundant per-lane stats, normalize, NORMAL stores (A/B vs round-10's NT stores).
__global__ __launch_bounds__(128) void k_fused(
    const float* __restrict__ pc, const int* __restrict__ i_frustum,
    const float* __restrict__ counts, int n, int F,
    float* __restrict__ out_mean, float* __restrict__ out_std,
    float* __restrict__ out_max, float* __restrict__ out_pcn)
{
    const int wid = (blockIdx.x * blockDim.x + threadIdx.x) >> 6;  // global wave id
    if (wid >= F) return;                                          // wave-uniform exit
    const int lane = threadIdx.x & 63;

    const int s = wave_lower_bound(i_frustum, n, wid, lane);
    const float cnt = counts[wid];
    const int e = s + (int)cnt;      // counts are small integers, exact in float

    const float4* __restrict__ pc4 = reinterpret_cast<const float4*>(pc);
    v4f* __restrict__ out4 = reinterpret_cast<v4f*>(out_pcn);

    const int b = s * 2, E = e * 2;  // float4-granular range (NCH=8 -> 2 float4/point)

    float4 sum = {0.f, 0.f, 0.f, 0.f};
    float4 sq  = {0.f, 0.f, 0.f, 0.f};
    float4 mx  = {0.f, 0.f, 0.f, 0.f};  // 0-init == scatter-max onto zeros (include_self)
    float4 c[CACHE];

    int k = b + lane;
    #pragma unroll
    for (int u = 0; u < CACHE; ++u) {
        if (k < E) { c[u] = pc4[k]; acc4(c[u], sum, sq, mx); }
        k += 64;
    }
    for (int kk = k; kk < E; kk += 64) { float4 v = pc4[kk]; acc4(v, sum, sq, mx); }  // rare

    // Lane parity p = lane&1 owns channels [4p, 4p+4). Reduce lanes differing in bits 1..5.
    #pragma unroll
    for (int m = 2; m <= 32; m <<= 1) {
        sum.x += __shfl_xor(sum.x, m, 64);
        sum.y += __shfl_xor(sum.y, m, 64);
        sum.z += __shfl_xor(sum.z, m, 64);
        sum.w += __shfl_xor(sum.w, m, 64);
        sq.x  += __shfl_xor(sq.x,  m, 64);
        sq.y  += __shfl_xor(sq.y,  m, 64);
        sq.z  += __shfl_xor(sq.z,  m, 64);
        sq.w  += __shfl_xor(sq.w,  m, 64);
        mx.x = fmaxf(mx.x, __shfl_xor(mx.x, m, 64));
        mx.y = fmaxf(mx.y, __shfl_xor(mx.y, m, 64));
        mx.z = fmaxf(mx.z, __shfl_xor(mx.z, m, 64));
        mx.w = fmaxf(mx.w, __shfl_xor(mx.w, m, 64));
    }

    // Every lane holds its parity-group totals; compute stats redundantly (cheap).
    const float invc = 1.0f / fmaxf(cnt, 1.0f);
    float4 mean, sd, dv;
    mean.x = sum.x * invc; mean.y = sum.y * invc; mean.z = sum.z * invc; mean.w = sum.w * invc;
    float vx = fmaxf(sq.x * invc - mean.x * mean.x, 0.0f);
    float vy = fmaxf(sq.y * invc - mean.y * mean.y, 0.0f);
    float vz = fmaxf(sq.z * invc - mean.z * mean.z, 0.0f);
    float vw = fmaxf(sq.w * invc - mean.w * mean.w, 0.0f);
    sd.x = sqrtf(vx); sd.y = sqrtf(vy); sd.z = sqrtf(vz); sd.w = sqrtf(vw);
    dv.x = 1.0f / (sd.x > 0.f ? sd.x : 1.f);
    dv.y = 1.0f / (sd.y > 0.f ? sd.y : 1.f);
    dv.z = 1.0f / (sd.z > 0.f ? sd.z : 1.f);
    dv.w = 1.0f / (sd.w > 0.f ? sd.w : 1.f);

    if (lane < 2) {  // lane 0 -> channels 0-3, lane 1 -> channels 4-7
        reinterpret_cast<float4*>(out_mean + (size_t)wid * NCH)[lane] = mean;
        reinterpret_cast<float4*>(out_std  + (size_t)wid * NCH)[lane] = sd;
        reinterpret_cast<float4*>(out_max  + (size_t)wid * NCH)[lane] = mx;
    }

    // Normalize from the cached values; NORMAL stores (through L2 write-combining).
    k = b + lane;
    #pragma unroll
    for (int u = 0; u < CACHE; ++u) {
        if (k < E) out4[k] = norm4(c[u], mean, dv);
        k += 64;
    }
    for (int kk = k; kk < E; kk += 64) {  // rare
        out4[kk] = norm4(pc4[kk], mean, dv);
    }
}

extern "C" void kernel_launch(void* const* d_in, const int* in_sizes, int n_in,
                              void* d_out, int out_size, void* d_ws, size_t ws_size,
                              hipStream_t stream) {
    const float* pc        = (const float*)d_in[0];
    const int*   i_frustum = (const int*)d_in[1];
    const float* counts    = (const float*)d_in[3];

    int n = in_sizes[0] / NCH;   // 2,000,000 points
    int F = in_sizes[3];         // 14,400 frustums

    float* out_mean = (float*)d_out;
    float* out_std  = out_mean + (size_t)F * NCH;
    float* out_max  = out_std  + (size_t)F * NCH;
    float* out_pcn  = out_max  + (size_t)F * NCH;

    int waves_per_block = 128 / 64;
    int blocks = (F + waves_per_block - 1) / waves_per_block;
    k_fused<<<blocks, 128, 0, stream>>>(pc, i_frustum, counts, n, F,
                                        out_mean, out_std, out_max, out_pcn);
}

// Round 16
// 30.453 us; speedup vs baseline: 1.2365x; 1.0796x over previous
//
#include <hip/hip_runtime.h>

#define NCH 8
#define CACHE 8   // float4 per lane -> covers segments up to 256 points per frustum

typedef float v4f __attribute__((ext_vector_type(4)));

__device__ __forceinline__ void acc4(const float4& v, float4& sum, float4& sq, float4& mx) {
    sum.x += v.x; sq.x += v.x * v.x; mx.x = fmaxf(mx.x, v.x);
    sum.y += v.y; sq.y += v.y * v.y; mx.y = fmaxf(mx.y, v.y);
    sum.z += v.z; sq.z += v.z * v.z; mx.z = fmaxf(mx.z, v.z);
    sum.w += v.w; sq.w += v.w * v.w; mx.w = fmaxf(mx.w, v.w);
}

__device__ __forceinline__ v4f norm4(const float4& v, const float4& m, const float4& d) {
    v4f o;
    o.x = (v.x - m.x) * d.x;
    o.y = (v.y - m.y) * d.y;
    o.z = (v.z - m.z) * d.z;
    o.w = (v.w - m.w) * d.w;
    return o;
}

// Wave-cooperative lower_bound: smallest idx with a[idx] >= key. 4 memory rounds for n=2M.
__device__ __forceinline__ int wave_lower_bound(const int* __restrict__ a, int n, int key,
                                                int lane) {
    int lo = 0, len = n;
    while (len > 64) {
        int step = (len + 63) >> 6;                       // ceil(len/64)
        int p = lo + lane * step;
        int v = (p < lo + len) ? a[p] : 0x7fffffff;
        unsigned long long bal = __ballot(v < key);
        int cnt = __popcll(bal);                          // preds form a prefix (sorted)
        if (cnt == 0) return lo;
        int nlo = lo + (cnt - 1) * step + 1;
        int nhi = lo + len;
        int cap = lo + cnt * step;
        if (cnt < 64 && cap < nhi) nhi = cap;
        lo = nlo; len = nhi - nlo;
    }
    int v = (lane < len) ? a[lo + lane] : 0x7fffffff;
    unsigned long long bal = __ballot(v < key);
    return lo + __popcll(bal);
}

// One WAVE per frustum, fused search+stats+normalize. KEY CHANGE vs round 10:
// loads are issued in a separate loop BEFORE any accumulation, so all 8 float4
// loads are in flight concurrently (R13 showed this makes the compiler keep the
// register cache live: VGPR ~68 vs 40 with interleaved load+acc).
__global__ __launch_bounds__(128) void k_fused(
    const float* __restrict__ pc, const int* __restrict__ i_frustum,
    const float* __restrict__ counts, int n, int F,
    float* __restrict__ out_mean, float* __restrict__ out_std,
    float* __restrict__ out_max, float* __restrict__ out_pcn)
{
    const int wid = (blockIdx.x * blockDim.x + threadIdx.x) >> 6;  // global wave id
    if (wid >= F) return;                                          // wave-uniform exit
    const int lane = threadIdx.x & 63;

    const int s = wave_lower_bound(i_frustum, n, wid, lane);
    const float cnt = counts[wid];
    const int e = s + (int)cnt;      // counts are small integers, exact in float

    const float4* __restrict__ pc4 = reinterpret_cast<const float4*>(pc);
    v4f* __restrict__ out4 = reinterpret_cast<v4f*>(out_pcn);

    const int b = s * 2, E = e * 2;  // float4-granular range (NCH=8 -> 2 float4/point)

    float4 sum = {0.f, 0.f, 0.f, 0.f};
    float4 sq  = {0.f, 0.f, 0.f, 0.f};
    float4 mx  = {0.f, 0.f, 0.f, 0.f};  // 0-init == scatter-max onto zeros (include_self)
    float4 c[CACHE];

    // Phase 1: issue ALL loads (predicated) back-to-back -> 8 outstanding per lane.
    int k = b + lane;
    #pragma unroll
    for (int u = 0; u < CACHE; ++u) {
        if (k < E) c[u] = pc4[k];
        k += 64;
    }
    // Phase 2: accumulate from the register cache.
    k = b + lane;
    #pragma unroll
    for (int u = 0; u < CACHE; ++u) {
        if (k < E) acc4(c[u], sum, sq, mx);
        k += 64;
    }
    for (int kk = k; kk < E; kk += 64) { float4 v = pc4[kk]; acc4(v, sum, sq, mx); }  // rare

    // Lane parity p = lane&1 owns channels [4p, 4p+4). Reduce lanes differing in bits 1..5.
    #pragma unroll
    for (int m = 2; m <= 32; m <<= 1) {
        sum.x += __shfl_xor(sum.x, m, 64);
        sum.y += __shfl_xor(sum.y, m, 64);
        sum.z += __shfl_xor(sum.z, m, 64);
        sum.w += __shfl_xor(sum.w, m, 64);
        sq.x  += __shfl_xor(sq.x,  m, 64);
        sq.y  += __shfl_xor(sq.y,  m, 64);
        sq.z  += __shfl_xor(sq.z,  m, 64);
        sq.w  += __shfl_xor(sq.w,  m, 64);
        mx.x = fmaxf(mx.x, __shfl_xor(mx.x, m, 64));
        mx.y = fmaxf(mx.y, __shfl_xor(mx.y, m, 64));
        mx.z = fmaxf(mx.z, __shfl_xor(mx.z, m, 64));
        mx.w = fmaxf(mx.w, __shfl_xor(mx.w, m, 64));
    }

    // Every lane holds its parity-group totals; compute stats redundantly (cheap).
    const float invc = 1.0f / fmaxf(cnt, 1.0f);
    float4 mean, sd, dv;
    mean.x = sum.x * invc; mean.y = sum.y * invc; mean.z = sum.z * invc; mean.w = sum.w * invc;
    float vx = fmaxf(sq.x * invc - mean.x * mean.x, 0.0f);
    float vy = fmaxf(sq.y * invc - mean.y * mean.y, 0.0f);
    float vz = fmaxf(sq.z * invc - mean.z * mean.z, 0.0f);
    float vw = fmaxf(sq.w * invc - mean.w * mean.w, 0.0f);
    sd.x = sqrtf(vx); sd.y = sqrtf(vy); sd.z = sqrtf(vz); sd.w = sqrtf(vw);
    dv.x = 1.0f / (sd.x > 0.f ? sd.x : 1.f);
    dv.y = 1.0f / (sd.y > 0.f ? sd.y : 1.f);
    dv.z = 1.0f / (sd.z > 0.f ? sd.z : 1.f);
    dv.w = 1.0f / (sd.w > 0.f ? sd.w : 1.f);

    if (lane < 2) {  // lane 0 -> channels 0-3, lane 1 -> channels 4-7
        reinterpret_cast<float4*>(out_mean + (size_t)wid * NCH)[lane] = mean;
        reinterpret_cast<float4*>(out_std  + (size_t)wid * NCH)[lane] = sd;
        reinterpret_cast<float4*>(out_max  + (size_t)wid * NCH)[lane] = mx;
    }

    // Normalize from the register cache; NT stores (output never re-read).
    k = b + lane;
    #pragma unroll
    for (int u = 0; u < CACHE; ++u) {
        if (k < E) {
            v4f o = norm4(c[u], mean, dv);
            __builtin_nontemporal_store(o, &out4[k]);
        }
        k += 64;
    }
    for (int kk = k; kk < E; kk += 64) {  // rare
        v4f o = norm4(pc4[kk], mean, dv);
        __builtin_nontemporal_store(o, &out4[kk]);
    }
}

extern "C" void kernel_launch(void* const* d_in, const int* in_sizes, int n_in,
                              void* d_out, int out_size, void* d_ws, size_t ws_size,
                              hipStream_t stream) {
    const float* pc        = (const float*)d_in[0];
    const int*   i_frustum = (const int*)d_in[1];
    const float* counts    = (const float*)d_in[3];

    int n = in_sizes[0] / NCH;   // 2,000,000 points
    int F = in_sizes[3];         // 14,400 frustums

    float* out_mean = (float*)d_out;
    float* out_std  = out_mean + (size_t)F * NCH;
    float* out_max  = out_std  + (size_t)F * NCH;
    float* out_pcn  = out_max  + (size_t)F * NCH;

    int waves_per_block = 128 / 64;
    int blocks = (F + waves_per_block - 1) / waves_per_block;
    k_fused<<<blocks, 128, 0, stream>>>(pc, i_frustum, counts, n, F,
                                        out_mean, out_std, out_max, out_pcn);
}

// Round 17
// 30.135 us; speedup vs baseline: 1.2496x; 1.0106x over previous
//
#include <hip/hip_runtime.h>

#define NCH 8
#define CACHE 8   // float4 per lane -> covers segments up to 256 points per frustum

typedef float v4f __attribute__((ext_vector_type(4)));

__device__ __forceinline__ v4f norm4(const float4& v, const float4& m, const float4& d) {
    v4f o;
    o.x = (v.x - m.x) * d.x;
    o.y = (v.y - m.y) * d.y;
    o.z = (v.z - m.z) * d.z;
    o.w = (v.w - m.w) * d.w;
    return o;
}

// Wave-cooperative lower_bound: smallest idx with a[idx] >= key. 4 memory rounds for n=2M.
__device__ __forceinline__ int wave_lower_bound(const int* __restrict__ a, int n, int key,
                                                int lane) {
    int lo = 0, len = n;
    while (len > 64) {
        int step = (len + 63) >> 6;                       // ceil(len/64)
        int p = lo + lane * step;
        int v = (p < lo + len) ? a[p] : 0x7fffffff;
        unsigned long long bal = __ballot(v < key);
        int cnt = __popcll(bal);                          // preds form a prefix (sorted)
        if (cnt == 0) return lo;
        int nlo = lo + (cnt - 1) * step + 1;
        int nhi = lo + len;
        int cap = lo + cnt * step;
        if (cnt < 64 && cap < nhi) nhi = cap;
        lo = nlo; len = nhi - nlo;
    }
    int v = (lane < len) ? a[lo + lane] : 0x7fffffff;
    unsigned long long bal = __ballot(v < key);
    return lo + __popcll(bal);
}

// One WAVE per frustum, fused search+stats+normalize. KEY CHANGE vs round 16:
// loads are UNCONDITIONAL with clamped index (no exec-mask, no branch) so the
// compiler must issue all 8 global_load_dwordx4 back-to-back -> 8 outstanding
// per lane. Out-of-range elements are masked to 0 at accumulate time (0 is the
// identity for sum, sumsq, AND max-vs-0 include_self semantics).
__global__ __launch_bounds__(128) void k_fused(
    const float* __restrict__ pc, const int* __restrict__ i_frustum,
    const float* __restrict__ counts, int n, int F,
    float* __restrict__ out_mean, float* __restrict__ out_std,
    float* __restrict__ out_max, float* __restrict__ out_pcn)
{
    const int wid = (blockIdx.x * blockDim.x + threadIdx.x) >> 6;  // global wave id
    if (wid >= F) return;                                          // wave-uniform exit
    const int lane = threadIdx.x & 63;

    const int s = wave_lower_bound(i_frustum, n, wid, lane);
    const float cnt = counts[wid];
    const int e = s + (int)cnt;      // counts are small integers, exact in float

    const float4* __restrict__ pc4 = reinterpret_cast<const float4*>(pc);
    v4f* __restrict__ out4 = reinterpret_cast<v4f*>(out_pcn);

    const int b = s * 2, E = e * 2;  // float4-granular range (NCH=8 -> 2 float4/point)
    const int lim = max(E - 1, 0);   // clamp target (empty segment -> index 0, masked off)

    float4 sum = {0.f, 0.f, 0.f, 0.f};
    float4 sq  = {0.f, 0.f, 0.f, 0.f};
    float4 mx  = {0.f, 0.f, 0.f, 0.f};  // 0-init == scatter-max onto zeros (include_self)
    float4 c[CACHE];

    // Phase 1: unconditional clamped loads -> all 8 issue back-to-back.
    {
        int k = b + lane;
        #pragma unroll
        for (int u = 0; u < CACHE; ++u) {
            c[u] = pc4[min(k, lim)];
            k += 64;
        }
    }
    // Phase 2: branchless masked accumulate (cndmask, no flow control).
    {
        int k = b + lane;
        #pragma unroll
        for (int u = 0; u < CACHE; ++u) {
            const bool in = k < E;
            float vx = in ? c[u].x : 0.f, vy = in ? c[u].y : 0.f;
            float vz = in ? c[u].z : 0.f, vw = in ? c[u].w : 0.f;
            sum.x += vx; sq.x += vx * vx; mx.x = fmaxf(mx.x, vx);
            sum.y += vy; sq.y += vy * vy; mx.y = fmaxf(mx.y, vy);
            sum.z += vz; sq.z += vz * vz; mx.z = fmaxf(mx.z, vz);
            sum.w += vw; sq.w += vw * vw; mx.w = fmaxf(mx.w, vw);
            k += 64;
        }
        for (int kk = b + lane + CACHE * 64; kk < E; kk += 64) {  // rare overflow
            float4 v = pc4[kk];
            sum.x += v.x; sq.x += v.x * v.x; mx.x = fmaxf(mx.x, v.x);
            sum.y += v.y; sq.y += v.y * v.y; mx.y = fmaxf(mx.y, v.y);
            sum.z += v.z; sq.z += v.z * v.z; mx.z = fmaxf(mx.z, v.z);
            sum.w += v.w; sq.w += v.w * v.w; mx.w = fmaxf(mx.w, v.w);
        }
    }

    // Lane parity p = lane&1 owns channels [4p, 4p+4). Reduce lanes differing in bits 1..5.
    #pragma unroll
    for (int m = 2; m <= 32; m <<= 1) {
        sum.x += __shfl_xor(sum.x, m, 64);
        sum.y += __shfl_xor(sum.y, m, 64);
        sum.z += __shfl_xor(sum.z, m, 64);
        sum.w += __shfl_xor(sum.w, m, 64);
        sq.x  += __shfl_xor(sq.x,  m, 64);
        sq.y  += __shfl_xor(sq.y,  m, 64);
        sq.z  += __shfl_xor(sq.z,  m, 64);
        sq.w  += __shfl_xor(sq.w,  m, 64);
        mx.x = fmaxf(mx.x, __shfl_xor(mx.x, m, 64));
        mx.y = fmaxf(mx.y, __shfl_xor(mx.y, m, 64));
        mx.z = fmaxf(mx.z, __shfl_xor(mx.z, m, 64));
        mx.w = fmaxf(mx.w, __shfl_xor(mx.w, m, 64));
    }

    // Every lane holds its parity-group totals; compute stats redundantly (cheap).
    const float invc = 1.0f / fmaxf(cnt, 1.0f);
    float4 mean, sd, dv;
    mean.x = sum.x * invc; mean.y = sum.y * invc; mean.z = sum.z * invc; mean.w = sum.w * invc;
    float vx = fmaxf(sq.x * invc - mean.x * mean.x, 0.0f);
    float vy = fmaxf(sq.y * invc - mean.y * mean.y, 0.0f);
    float vz = fmaxf(sq.z * invc - mean.z * mean.z, 0.0f);
    float vw = fmaxf(sq.w * invc - mean.w * mean.w, 0.0f);
    sd.x = sqrtf(vx); sd.y = sqrtf(vy); sd.z = sqrtf(vz); sd.w = sqrtf(vw);
    dv.x = 1.0f / (sd.x > 0.f ? sd.x : 1.f);
    dv.y = 1.0f / (sd.y > 0.f ? sd.y : 1.f);
    dv.z = 1.0f / (sd.z > 0.f ? sd.z : 1.f);
    dv.w = 1.0f / (sd.w > 0.f ? sd.w : 1.f);

    if (lane < 2) {  // lane 0 -> channels 0-3, lane 1 -> channels 4-7
        reinterpret_cast<float4*>(out_mean + (size_t)wid * NCH)[lane] = mean;
        reinterpret_cast<float4*>(out_std  + (size_t)wid * NCH)[lane] = sd;
        reinterpret_cast<float4*>(out_max  + (size_t)wid * NCH)[lane] = mx;
    }

    // Normalize from the register cache; NT stores (output never re-read).
    {
        int k = b + lane;
        #pragma unroll
        for (int u = 0; u < CACHE; ++u) {
            if (k < E) {
                v4f o = norm4(c[u], mean, dv);
                __builtin_nontemporal_store(o, &out4[k]);
            }
            k += 64;
        }
        for (int kk = b + lane + CACHE * 64; kk < E; kk += 64) {  // rare
            v4f o = norm4(pc4[kk], mean, dv);
            __builtin_nontemporal_store(o, &out4[kk]);
        }
    }
}

extern "C" void kernel_launch(void* const* d_in, const int* in_sizes, int n_in,
                              void* d_out, int out_size, void* d_ws, size_t ws_size,
                              hipStream_t stream) {
    const float* pc        = (const float*)d_in[0];
    const int*   i_frustum = (const int*)d_in[1];
    const float* counts    = (const float*)d_in[3];

    int n = in_sizes[0] / NCH;   // 2,000,000 points
    int F = in_sizes[3];         // 14,400 frustums

    float* out_mean = (float*)d_out;
    float* out_std  = out_mean + (size_t)F * NCH;
    float* out_max  = out_std  + (size_t)F * NCH;
    float* out_pcn  = out_max  + (size_t)F * NCH;

    int waves_per_block = 128 / 64;
    int blocks = (F + waves_per_block - 1) / waves_per_block;
    k_fused<<<blocks, 128, 0, stream>>>(pc, i_frustum, counts, n, F,
                                        out_mean, out_std, out_max, out_pcn);
}